// Round 3
// baseline (233.982 us; speedup 1.0000x reference)
//
#include <hip/hip_runtime.h>
#include <math.h>

#define T_STEPS 2048
#define NU 512
#define NCH 8192              // B*U independent chains
#define NGRP (T_STEPS / 4)    // 512 groups of 4 timesteps
#define PFG 10                // groups prefetched ahead (40 steps, 20KB/wave in flight)
#define RING 16               // LDS ring slots (power of 2 > PFG)

// vmcnt counting (all memory ops fenced by "memory"-clobber asm, so per-iteration
// op counts are exact): each full iteration issues 2 global_load_lds + 4 stores.
// Pair for group h=g+1 was issued at iteration s=g+1-PFG (or prologue).
//  Phase A (g<=8, pair from prologue):  ops-after-pair = 18+4g >= 18  -> vmcnt(18)
//  Phase B (9<=g<502):                  ops-after-pair = 4+6*(PFG-2)+2 = 54 -> vmcnt(54)
//  Phase C (g>=502, staging tailing off): min ops-after = 36          -> vmcnt(36)
#define WAIT_A asm volatile("s_waitcnt vmcnt(18)" ::: "memory")
#define WAIT_B asm volatile("s_waitcnt vmcnt(54)" ::: "memory")
#define WAIT_C asm volatile("s_waitcnt vmcnt(36)" ::: "memory")

__global__ __launch_bounds__(64)
void reshopf_kernel(const float* __restrict__ Xr, const float* __restrict__ Xi,
                    const float* __restrict__ r0, const float* __restrict__ phi0,
                    const float* __restrict__ omegas,
                    float* __restrict__ zr, float* __restrict__ r_f,
                    float* __restrict__ phi_f)
{
    // LDS ring: slot = [4 timesteps][64 chains] = 1KB per array. 32 KB total.
    __shared__ float lxr[RING][4][64];
    __shared__ float lxi[RING][4][64];

    const int lane  = threadIdx.x;
    const int wbase = blockIdx.x * 64;      // first chain of this wave
    const int g     = wbase + lane;         // this lane's chain id
    const int u     = g & (NU - 1);

    const float TWO_PI = 6.28318530717958647692f;
    const float INV2PI = 0.15915494309189533577f;

    // omega squash
    const float wo  = omegas[u];
    const float sig = 1.0f / (1.0f + __expf(-wo));
    const float omdt     = (sig * 19.5f + 0.5f) * TWO_PI * 0.01f;  // rad/step
    const float omdt_rev = omdt * INV2PI;                          // rev/step

    float  r        = r0[g];
    const float p0  = phi0[g];
    double phi_full = (double)p0;
    float  phi_rev  = p0 * INV2PI;
    float  s = __builtin_amdgcn_sinf(phi_rev);
    float  c = __builtin_amdgcn_cosf(phi_rev);

    // staging lane map: lane -> (t_sub = lane>>4, 4 chains at (lane&15)*4).
    // One width-16 global_load_lds stages 4 timesteps x 64 chains (1KB, linear).
    const int t_sub = lane >> 4;
    const int coff  = (lane & 15) << 2;
    const float* sXr = Xr + (size_t)t_sub * NCH + wbase + coff;
    const float* sXi = Xi + (size_t)t_sub * NCH + wbase + coff;

    auto stage = [&](int gg) {
        const float* gr = sXr + ((size_t)gg * 4) * NCH;
        const float* gi = sXi + ((size_t)gg * 4) * NCH;
        __builtin_amdgcn_global_load_lds(
            (const __attribute__((address_space(1))) void*)gr,
            (__attribute__((address_space(3))) void*)&lxr[gg & (RING - 1)][0][0],
            16, 0, 0);
        __builtin_amdgcn_global_load_lds(
            (const __attribute__((address_space(1))) void*)gi,
            (__attribute__((address_space(3))) void*)&lxi[gg & (RING - 1)][0][0],
            16, 0, 0);
    };

    // prologue: fill the pipe
#pragma unroll
    for (int p = 0; p < PFG; ++p) stage(p);

    // wait for group 0 (ops issued after its pair = 18), read it into regs
    WAIT_A;
    float cxr0 = lxr[0][0][lane], cxr1 = lxr[0][1][lane];
    float cxr2 = lxr[0][2][lane], cxr3 = lxr[0][3][lane];
    float cxi0 = lxi[0][0][lane], cxi1 = lxi[0][1][lane];
    float cxi2 = lxi[0][2][lane], cxi3 = lxi[0][3][lane];

    float* pz = zr + g;

    auto step = [&](int t, float xr, float xi) {
        // phi += (om - 5*xi*sin(phi_old)) * DT ; tracked in revolutions
        const float cxi      = xi * -0.05f;
        const float dphi_rad = fmaf(cxi, s, omdt);
        const float dphi_rev = fmaf(cxi * INV2PI, s, omdt_rev);
        phi_rev = __builtin_amdgcn_fractf(phi_rev + dphi_rev);

        // r += ((1 - r^2)*r + 5*xr*cos(phi_old)) * DT
        const float rr = r * r;
        const float g1 = fmaf(-rr, r, r);
        r = fmaf(0.01f, g1, fmaf(0.05f * xr, c, r));

        // sincos of NEW phi: feeds Re(z) now, feedback next step
        s = __builtin_amdgcn_sinf(phi_rev);
        c = __builtin_amdgcn_cosf(phi_rev);
        phi_full += (double)dphi_rad;   // f64 phase for phi_f, off critical path

        __builtin_nontemporal_store(r * c, &pz[(size_t)t * NCH]);
    };

    for (int gi = 0; gi < NGRP; ++gi) {
        if (gi + PFG < NGRP) stage(gi + PFG);

        float nxr0, nxr1, nxr2, nxr3, nxi0, nxi1, nxi2, nxi3;
        const bool have_next = (gi + 1 < NGRP);
        if (have_next) {
            if (gi <= PFG - 2)            WAIT_A;   // pair from prologue
            else if (gi < NGRP - PFG)     WAIT_B;   // steady state
            else                          WAIT_C;   // staging tail
            const int ns = (gi + 1) & (RING - 1);
            nxr0 = lxr[ns][0][lane]; nxr1 = lxr[ns][1][lane];
            nxr2 = lxr[ns][2][lane]; nxr3 = lxr[ns][3][lane];
            nxi0 = lxi[ns][0][lane]; nxi1 = lxi[ns][1][lane];
            nxi2 = lxi[ns][2][lane]; nxi3 = lxi[ns][3][lane];
        }

        const int t0 = gi * 4;
        step(t0 + 0, cxr0, cxi0);
        step(t0 + 1, cxr1, cxi1);
        step(t0 + 2, cxr2, cxi2);
        step(t0 + 3, cxr3, cxi3);

        if (have_next) {
            cxr0 = nxr0; cxr1 = nxr1; cxr2 = nxr2; cxr3 = nxr3;
            cxi0 = nxi0; cxi1 = nxi1; cxi2 = nxi2; cxi3 = nxi3;
        }
    }

    r_f[g]   = r;
    phi_f[g] = (float)phi_full;
}

extern "C" void kernel_launch(void* const* d_in, const int* in_sizes, int n_in,
                              void* d_out, int out_size, void* d_ws, size_t ws_size,
                              hipStream_t stream) {
    const float* Xr   = (const float*)d_in[0];
    const float* Xi   = (const float*)d_in[1];
    const float* r0   = (const float*)d_in[2];
    const float* phi0 = (const float*)d_in[3];
    const float* om   = (const float*)d_in[4];

    float* out   = (float*)d_out;
    float* zrp   = out;                               // Re(z): T*NCH floats
    float* r_f   = out + (size_t)T_STEPS * NCH;       // NCH floats
    float* phi_f = r_f + NCH;                         // NCH floats

    reshopf_kernel<<<NCH / 64, 64, 0, stream>>>(Xr, Xi, r0, phi0, om, zrp, r_f, phi_f);
}

// Round 4
// 107.928 us; speedup vs baseline: 2.1679x; 2.1679x over previous
//
#include <hip/hip_runtime.h>
#include <math.h>
#include <type_traits>

#define T_STEPS 2048
#define NU 512
#define NCH 8192            // B*U independent chains
#define NGRP 512            // groups of 4 timesteps
#define PFG 11              // groups in flight (22KB/wave reads)
#define RING 16             // LDS ring slots

typedef float f2 __attribute__((ext_vector_type(2)));
template<int N> using ic = std::integral_constant<int, N>;

// vmcnt accounting (exact: every wait-asm has "memory" clobber, so no vmem op
// can cross it; ops per fence interval are therefore fixed):
//   iteration layout: [WAITVM][4x ds_read(asm, lgkm only)][lgkm(4)+schedbar]
//                     [stage: 2 global_load_lds][compute: 4 nontemporal stores]
//   pair(g+1) staged mid-iteration s=g+1-PFG =>
//     phase A (pair from prologue, g=0..9):  N = 2*(PFG-2-g) + 6g = 18+4g
//     steady (g>=10):                        N = 4 + 6*(PFG-2) + 0 = 58
//   max outstanding at wait = N+2 = 60 <= 63.
__global__ __launch_bounds__(64)
void reshopf_kernel(const float* __restrict__ Xr, const float* __restrict__ Xi,
                    const float* __restrict__ r0, const float* __restrict__ phi0,
                    const float* __restrict__ omegas,
                    float* __restrict__ zr, float* __restrict__ r_f,
                    float* __restrict__ phi_f)
{
    __shared__ float ldsR[RING][4][64];   // [slot][t_sub][chain] 1KB/slot
    __shared__ float ldsI[RING][4][64];

    const int lane  = threadIdx.x;
    const int wbase = blockIdx.x * 64;
    const int g     = wbase + lane;
    const int u     = g & (NU - 1);

    const float INV2PI = 0.15915494309189533577f;
    const float K2     = -0.05f * INV2PI;          // -INPUT_SCALER*DT / 2pi

    const float wo  = omegas[u];
    const float sig = 1.0f / (1.0f + __expf(-wo));
    const float omdt_rev = (sig * 19.5f + 0.5f) * 0.01f;   // rev/step

    float r        = r0[g];
    const float p0 = phi0[g];
    float phi_rev  = p0 * INV2PI;
    float s = __builtin_amdgcn_sinf(phi_rev);
    float c = __builtin_amdgcn_cosf(phi_rev);
    float acc2 = 0.0f;                              // sum of cxi2*s (revolutions)

    // staging lane map: one width-16 global_load_lds = 4 timesteps x 64 chains
    const int t_sub = lane >> 4;
    const int coff  = (lane & 15) << 2;
    const float* sXr = Xr + (size_t)t_sub * NCH + wbase + coff;
    const float* sXi = Xi + (size_t)t_sub * NCH + wbase + coff;

    const unsigned ldsRb = (unsigned)(uintptr_t)&ldsR[0][0][0] + (unsigned)lane * 4u;
    const unsigned ldsIb = (unsigned)(uintptr_t)&ldsI[0][0][0] + (unsigned)lane * 4u;

    auto stage = [&](int gg) {
        const int gsrc = (gg < NGRP) ? gg : (NGRP - 1);   // tail: restage last grp
        const int slot = gg & (RING - 1);                 // slot keeps advancing
        const float* ar = sXr + ((size_t)gsrc << 15);     // gsrc*4*NCH floats
        const float* ai = sXi + ((size_t)gsrc << 15);
        __builtin_amdgcn_global_load_lds(
            (const __attribute__((address_space(1))) void*)ar,
            (__attribute__((address_space(3))) void*)&ldsR[slot][0][0], 16, 0, 0);
        __builtin_amdgcn_global_load_lds(
            (const __attribute__((address_space(1))) void*)ai,
            (__attribute__((address_space(3))) void*)&ldsI[slot][0][0], 16, 0, 0);
    };

    // invisible-to-compiler LDS reads (lgkm only; no "memory" so no auto-waits)
    auto lds_read = [&](int grp, f2& r01, f2& r23, f2& i01, f2& i23) {
        const unsigned so = (unsigned)(grp & (RING - 1)) << 10;
        const unsigned ar = ldsRb + so;
        const unsigned ai = ldsIb + so;
        asm volatile("ds_read2_b32 %0, %1 offset0:0 offset1:64"    : "=v"(r01) : "v"(ar));
        asm volatile("ds_read2_b32 %0, %1 offset0:128 offset1:192" : "=v"(r23) : "v"(ar));
        asm volatile("ds_read2_b32 %0, %1 offset0:0 offset1:64"    : "=v"(i01) : "v"(ai));
        asm volatile("ds_read2_b32 %0, %1 offset0:128 offset1:192" : "=v"(i23) : "v"(ai));
    };

    float* pz = zr + g;
    auto step = [&](float xr, float xi) {
        const float cxi2 = xi * K2;                          // off critical path
        const float dphi = fmaf(cxi2, s, omdt_rev);          // rev
        phi_rev = __builtin_amdgcn_fractf(phi_rev + dphi);   // exact wrap
        acc2 = fmaf(cxi2, s, acc2);                          // phi_f accumulator
        const float rr = r * r;
        const float g1 = fmaf(-rr, r, r);                    // (1-r^2)*r
        r = fmaf(0.01f, g1, fmaf(xr * 0.05f, c, r));
        s = __builtin_amdgcn_sinf(phi_rev);                  // NEW phi
        c = __builtin_amdgcn_cosf(phi_rev);
        __builtin_nontemporal_store(r * c, pz);              // Re(z)
        pz += NCH;
    };

    f2 Ar01, Ar23, Ai01, Ai23;   // parity double-buffer (no reg-copy hazard)
    f2 Br01, Br23, Bi01, Bi23;

    auto iter = [&](auto NW, auto CA, auto HN, int gi) {
        if constexpr (decltype(HN)::value) {
            asm volatile("s_waitcnt vmcnt(%0)" :: "n"(decltype(NW)::value) : "memory");
            if constexpr (decltype(CA)::value) lds_read(gi + 1, Br01, Br23, Bi01, Bi23);
            else                               lds_read(gi + 1, Ar01, Ar23, Ai01, Ai23);
            asm volatile("s_waitcnt lgkmcnt(4)" ::: "memory");   // prev grp's reads done
        } else {
            asm volatile("s_waitcnt lgkmcnt(0)" ::: "memory");
        }
        __builtin_amdgcn_sched_barrier(0);                        // rule #18 fence
        if constexpr (decltype(HN)::value) stage(gi + PFG);
        if constexpr (decltype(CA)::value) {
            step(Ar01.x, Ai01.x); step(Ar01.y, Ai01.y);
            step(Ar23.x, Ai23.x); step(Ar23.y, Ai23.y);
        } else {
            step(Br01.x, Bi01.x); step(Br01.y, Bi01.y);
            step(Br23.x, Bi23.x); step(Br23.y, Bi23.y);
        }
    };

    // prologue: fill pipe, read group 0 into buffer A
#pragma unroll
    for (int p = 0; p < PFG; ++p) stage(p);
    asm volatile("s_waitcnt vmcnt(%0)" :: "n"(2 * (PFG - 1)) : "memory");
    lds_read(0, Ar01, Ar23, Ai01, Ai23);

    // phase A: waits ramp 18+4*gi while pairs come from the prologue
    iter(ic<18>{}, ic<1>{}, ic<1>{}, 0);
    iter(ic<22>{}, ic<0>{}, ic<1>{}, 1);
    iter(ic<26>{}, ic<1>{}, ic<1>{}, 2);
    iter(ic<30>{}, ic<0>{}, ic<1>{}, 3);
    iter(ic<34>{}, ic<1>{}, ic<1>{}, 4);
    iter(ic<38>{}, ic<0>{}, ic<1>{}, 5);
    iter(ic<42>{}, ic<1>{}, ic<1>{}, 6);
    iter(ic<46>{}, ic<0>{}, ic<1>{}, 7);
    iter(ic<50>{}, ic<1>{}, ic<1>{}, 8);
    iter(ic<54>{}, ic<0>{}, ic<1>{}, 9);

    // steady state: uniform 6 vmem ops/iter (tail restages keep it uniform)
    for (int gi = 10; gi < 510; gi += 2) {
        iter(ic<58>{}, ic<1>{}, ic<1>{}, gi);
        iter(ic<58>{}, ic<0>{}, ic<1>{}, gi + 1);
    }
    iter(ic<58>{}, ic<1>{}, ic<1>{}, 510);
    iter(ic<0>{},  ic<0>{}, ic<0>{}, 511);   // final: consume B, no prefetch

    r_f[g] = r;
    const double TWO_PI_D = 6.283185307179586476925286766559;
    phi_f[g] = (float)((double)p0 + ((double)omdt_rev * 2048.0 + (double)acc2) * TWO_PI_D);
}

extern "C" void kernel_launch(void* const* d_in, const int* in_sizes, int n_in,
                              void* d_out, int out_size, void* d_ws, size_t ws_size,
                              hipStream_t stream) {
    const float* Xr   = (const float*)d_in[0];
    const float* Xi   = (const float*)d_in[1];
    const float* r0   = (const float*)d_in[2];
    const float* phi0 = (const float*)d_in[3];
    const float* om   = (const float*)d_in[4];

    float* out   = (float*)d_out;
    float* zrp   = out;                               // Re(z): T*NCH floats
    float* r_f   = out + (size_t)T_STEPS * NCH;       // NCH floats
    float* phi_f = r_f + NCH;                         // NCH floats

    reshopf_kernel<<<NCH / 64, 64, 0, stream>>>(Xr, Xi, r0, phi0, om, zrp, r_f, phi_f);
}

// Round 5
// 103.408 us; speedup vs baseline: 2.2627x; 1.0437x over previous
//
#include <hip/hip_runtime.h>
#include <math.h>
#include <type_traits>

#define T_STEPS 2048
#define NU 512
#define NCH 8192            // B*U independent chains
#define NGRP 512            // groups of 4 timesteps
#define PFG 20              // groups in flight (40KB/wave reads)
#define RING 32             // LDS ring slots

typedef float f2 __attribute__((ext_vector_type(2)));
typedef float f4 __attribute__((ext_vector_type(4)));
template<int N> using ic = std::integral_constant<int, N>;

// vmcnt accounting (ops fenced by "memory"-clobber waits; conservative under
// stage<->store commuting inside one fence window):
//   prologue: 40 loads (pair(k) = ops 2k,2k+1)
//   iter 0:   2 loads (no store);  iter g>=1: 2 loads + 1 dwordx4 store
//   Nv(0)=36, Nv(1)=36, Nv(2..18)=35+g, steady(g>=19)=54.
//   max outstanding = 54+3 = 57 < 63 (never hits the 64-cap issue stall).
// lgkm accounting (DS ops retire in order; global_load_lds does NOT count in
// lgkm — proven by round 4 passing):
//   per iter: [1 zread b128][4 input ds_read2] ... [2 ds_write2]
//   inputs(g) ready: after-batch = 2 writes + 1 zread + 4 reads = 7
//   ztile(g-1) reg valid (pre-store): after b128 = 4 reads + 2 writes = 6
__global__ __launch_bounds__(64)
void reshopf_kernel(const float* __restrict__ Xr, const float* __restrict__ Xi,
                    const float* __restrict__ r0, const float* __restrict__ phi0,
                    const float* __restrict__ omegas,
                    float* __restrict__ zr, float* __restrict__ r_f,
                    float* __restrict__ phi_f)
{
    __shared__ float ldsR[RING][4][64];   // input ring: 1KB/slot
    __shared__ float ldsI[RING][4][64];
    __shared__ float ldsZ[2][4][64];      // z transpose tile, double-buffered

    const int lane  = threadIdx.x;
    const int wbase = blockIdx.x * 64;
    const int g     = wbase + lane;
    const int u     = g & (NU - 1);

    const float INV2PI = 0.15915494309189533577f;
    const float K2     = -0.05f * INV2PI;          // -INPUT_SCALER*DT / 2pi

    const float wo  = omegas[u];
    const float sig = 1.0f / (1.0f + __expf(-wo));
    const float omdt_rev = (sig * 19.5f + 0.5f) * 0.01f;   // rev/step

    float r        = r0[g];
    const float p0 = phi0[g];
    float phi_rev  = p0 * INV2PI;
    float s = __builtin_amdgcn_sinf(phi_rev);
    float c = __builtin_amdgcn_cosf(phi_rev);
    float acc2 = 0.0f;                              // sum of cxi2*s (revolutions)

    // staging lane map: one width-16 global_load_lds = 4 timesteps x 64 chains
    const int t_sub = lane >> 4;
    const int coff  = (lane & 15) << 2;
    const float* sXr = Xr + (size_t)t_sub * NCH + wbase + coff;
    const float* sXi = Xi + (size_t)t_sub * NCH + wbase + coff;

    const unsigned ldsRb = (unsigned)(uintptr_t)&ldsR[0][0][0] + (unsigned)lane * 4u;
    const unsigned ldsIb = (unsigned)(uintptr_t)&ldsI[0][0][0] + (unsigned)lane * 4u;
    const unsigned ldsZw = (unsigned)(uintptr_t)&ldsZ[0][0][0] + (unsigned)lane * 4u;
    const unsigned ldsZr = (unsigned)(uintptr_t)&ldsZ[0][0][0]
                         + (unsigned)(lane >> 4) * 256u + (unsigned)(lane & 15) * 16u;

    auto stage = [&](int gg) {
        const int gsrc = (gg < NGRP) ? gg : (NGRP - 1);   // tail: restage last grp
        const int slot = gg & (RING - 1);
        const float* ar = sXr + ((size_t)gsrc << 15);     // gsrc*4*NCH floats
        const float* ai = sXi + ((size_t)gsrc << 15);
        __builtin_amdgcn_global_load_lds(
            (const __attribute__((address_space(1))) void*)ar,
            (__attribute__((address_space(3))) void*)&ldsR[slot][0][0], 16, 0, 0);
        __builtin_amdgcn_global_load_lds(
            (const __attribute__((address_space(1))) void*)ai,
            (__attribute__((address_space(3))) void*)&ldsI[slot][0][0], 16, 0, 0);
    };

    // invisible-to-compiler LDS ops (lgkm only; no auto-waits)
    auto lds_read = [&](int grp, f2& r01, f2& r23, f2& i01, f2& i23) {
        const unsigned so = (unsigned)(grp & (RING - 1)) << 10;
        const unsigned ar = ldsRb + so;
        const unsigned ai = ldsIb + so;
        asm volatile("ds_read2_b32 %0, %1 offset0:0 offset1:64"    : "=v"(r01) : "v"(ar));
        asm volatile("ds_read2_b32 %0, %1 offset0:128 offset1:192" : "=v"(r23) : "v"(ar));
        asm volatile("ds_read2_b32 %0, %1 offset0:0 offset1:64"    : "=v"(i01) : "v"(ai));
        asm volatile("ds_read2_b32 %0, %1 offset0:128 offset1:192" : "=v"(i23) : "v"(ai));
    };
    auto zwrite = [&](int par, float z0, float z1, float z2, float z3) {
        const unsigned a = ldsZw + (unsigned)par * 1024u;
        asm volatile("ds_write2_b32 %0, %1, %2 offset0:0 offset1:64"
                     :: "v"(a), "v"(z0), "v"(z1));
        asm volatile("ds_write2_b32 %0, %1, %2 offset0:128 offset1:192"
                     :: "v"(a), "v"(z2), "v"(z3));
    };
    auto zread = [&](int par, f4& zt) {
        const unsigned a = ldsZr + (unsigned)par * 1024u;
        asm volatile("ds_read_b128 %0, %1" : "=v"(zt) : "v"(a));
    };

    // z store pointer: tile of group gs -> rows 4*gs..4*gs+3, 16B per lane
    float* pzs = zr + (size_t)(lane >> 4) * NCH + wbase + ((lane & 15) << 2);

    auto step = [&](float xr, float xi, float& zout) {
        const float phib = phi_rev + omdt_rev;               // starts before s
        const float cxi2 = xi * K2;
        phi_rev = __builtin_amdgcn_fractf(fmaf(cxi2, s, phib)); // exact wrap
        acc2 = fmaf(cxi2, s, acc2);                          // phi_f accumulator
        const float rr = r * r;
        const float g1 = fmaf(-rr, r, r);                    // (1-r^2)*r
        r = fmaf(0.01f, g1, fmaf(xr * 0.05f, c, r));
        s = __builtin_amdgcn_sinf(phi_rev);                  // NEW phi
        c = __builtin_amdgcn_cosf(phi_rev);
        zout = r * c;                                        // Re(z)
    };

    f2 Ar01, Ar23, Ai01, Ai23;   // parity double-buffer for inputs
    f2 Br01, Br23, Bi01, Bi23;

    auto iter = [&](auto NV, auto CA, auto FIRST, int gi) {
        f4 zt;
        if constexpr (!decltype(FIRST)::value) zread((gi - 1) & 1, zt);
        asm volatile("s_waitcnt vmcnt(%0)" :: "n"(decltype(NV)::value) : "memory");
        if constexpr (decltype(CA)::value) lds_read(gi + 1, Br01, Br23, Bi01, Bi23);
        else                               lds_read(gi + 1, Ar01, Ar23, Ai01, Ai23);
        asm volatile("s_waitcnt lgkmcnt(%0)"
                     :: "n"(decltype(FIRST)::value ? 4 : 7) : "memory");
        __builtin_amdgcn_sched_barrier(0);
        stage(gi + PFG);
        float z0, z1, z2, z3;
        if constexpr (decltype(CA)::value) {
            step(Ar01.x, Ai01.x, z0); step(Ar01.y, Ai01.y, z1);
            step(Ar23.x, Ai23.x, z2); step(Ar23.y, Ai23.y, z3);
        } else {
            step(Br01.x, Bi01.x, z0); step(Br01.y, Bi01.y, z1);
            step(Br23.x, Bi23.x, z2); step(Br23.y, Bi23.y, z3);
        }
        zwrite(gi & 1, z0, z1, z2, z3);
        if constexpr (!decltype(FIRST)::value) {
            asm volatile("s_waitcnt lgkmcnt(6)" ::: "memory");  // zt valid (in-order DS)
            *(f4*)pzs = zt;                                     // dwordx4, L2-cached
            pzs += (size_t)4 * NCH;
        }
    };

    // prologue: fill pipe, read group 0 into buffer A
#pragma unroll
    for (int p = 0; p < PFG; ++p) stage(p);
    asm volatile("s_waitcnt vmcnt(%0)" :: "n"(2 * (PFG - 1)) : "memory");
    lds_read(0, Ar01, Ar23, Ai01, Ai23);

    // phase A: pairs come from the prologue (Nv ramps), consume A on even g
    iter(ic<36>{}, ic<1>{}, ic<1>{}, 0);
    iter(ic<36>{}, ic<0>{}, ic<0>{}, 1);
    iter(ic<37>{}, ic<1>{}, ic<0>{}, 2);
    iter(ic<38>{}, ic<0>{}, ic<0>{}, 3);
    iter(ic<39>{}, ic<1>{}, ic<0>{}, 4);
    iter(ic<40>{}, ic<0>{}, ic<0>{}, 5);
    iter(ic<41>{}, ic<1>{}, ic<0>{}, 6);
    iter(ic<42>{}, ic<0>{}, ic<0>{}, 7);
    iter(ic<43>{}, ic<1>{}, ic<0>{}, 8);
    iter(ic<44>{}, ic<0>{}, ic<0>{}, 9);
    iter(ic<45>{}, ic<1>{}, ic<0>{}, 10);
    iter(ic<46>{}, ic<0>{}, ic<0>{}, 11);
    iter(ic<47>{}, ic<1>{}, ic<0>{}, 12);
    iter(ic<48>{}, ic<0>{}, ic<0>{}, 13);
    iter(ic<49>{}, ic<1>{}, ic<0>{}, 14);
    iter(ic<50>{}, ic<0>{}, ic<0>{}, 15);
    iter(ic<51>{}, ic<1>{}, ic<0>{}, 16);
    iter(ic<52>{}, ic<0>{}, ic<0>{}, 17);
    iter(ic<53>{}, ic<1>{}, ic<0>{}, 18);
    iter(ic<54>{}, ic<0>{}, ic<0>{}, 19);

    // steady state (uniform cadence; tail restages keep Nv valid)
    for (int gi = 20; gi < 510; gi += 2) {
        iter(ic<54>{}, ic<1>{}, ic<0>{}, gi);
        iter(ic<54>{}, ic<0>{}, ic<0>{}, gi + 1);
    }
    iter(ic<54>{}, ic<1>{}, ic<0>{}, 510);

    // final iteration g=511 (consume B; inputs already in regs' pipeline)
    {
        f4 zt;
        zread(0, zt);                                       // ztile(510)
        asm volatile("s_waitcnt lgkmcnt(3)" ::: "memory");  // inputs(511) ready
        __builtin_amdgcn_sched_barrier(0);
        float z0, z1, z2, z3;
        step(Br01.x, Bi01.x, z0); step(Br01.y, Bi01.y, z1);
        step(Br23.x, Bi23.x, z2); step(Br23.y, Bi23.y, z3);
        zwrite(1, z0, z1, z2, z3);
        asm volatile("s_waitcnt lgkmcnt(2)" ::: "memory");
        *(f4*)pzs = zt;                                     // group 510
        pzs += (size_t)4 * NCH;
        f4 zt2;
        zread(1, zt2);                                      // ztile(511)
        asm volatile("s_waitcnt lgkmcnt(0)" ::: "memory");
        *(f4*)pzs = zt2;                                    // group 511
    }

    r_f[g] = r;
    const double TWO_PI_D = 6.283185307179586476925286766559;
    phi_f[g] = (float)((double)p0 + ((double)omdt_rev * 2048.0 + (double)acc2) * TWO_PI_D);
}

extern "C" void kernel_launch(void* const* d_in, const int* in_sizes, int n_in,
                              void* d_out, int out_size, void* d_ws, size_t ws_size,
                              hipStream_t stream) {
    const float* Xr   = (const float*)d_in[0];
    const float* Xi   = (const float*)d_in[1];
    const float* r0   = (const float*)d_in[2];
    const float* phi0 = (const float*)d_in[3];
    const float* om   = (const float*)d_in[4];

    float* out   = (float*)d_out;
    float* zrp   = out;                               // Re(z): T*NCH floats
    float* r_f   = out + (size_t)T_STEPS * NCH;       // NCH floats
    float* phi_f = r_f + NCH;                         // NCH floats

    reshopf_kernel<<<NCH / 64, 64, 0, stream>>>(Xr, Xi, r0, phi0, om, zrp, r_f, phi_f);
}